// Round 1
// baseline (1465.615 us; speedup 1.0000x reference)
//
#include <hip/hip_runtime.h>

// Problem: B=4, S=2048, D=1024, H=16, DK=64. EPS=1e-6.
// Outputs: x [4,2048,1024] fp32 then attn [4,16,2048,2048] fp32, concat flat.
//
// ws layout (bytes):
//   qh   [8192,1024] bf16  @ 0        (16 MB)  (already scaled by 1/8)
//   kh   [8192,1024] bf16  @ 16 MB
//   vhT  [64,64,2048] bf16 @ 32 MB    ([bh][d][s])
//   ctx  [8192,1024] bf16  @ 48 MB
//   WqT  [1024,1024] bf16  @ 64 MB    (B^T layout: [n][k])
//   WfcT [1024,1024] bf16  @ 66 MB
//   total 68 MB

typedef __attribute__((ext_vector_type(8))) short short8;
typedef __attribute__((ext_vector_type(4))) float f32x4;
typedef __attribute__((ext_vector_type(8))) unsigned short us8;
typedef __attribute__((ext_vector_type(4))) unsigned short us4;

__device__ __forceinline__ unsigned short f2bf(float f) {
  unsigned int u = __float_as_uint(f);
  u += 0x7FFFu + ((u >> 16) & 1u);
  return (unsigned short)(u >> 16);
}

#define MFMA16(a, b, c) __builtin_amdgcn_mfma_f32_16x16x32_bf16((a), (b), (c), 0, 0, 0)

// ---------------------------------------------------------------- transpose W
__global__ __launch_bounds__(256) void transpose_w(const float* __restrict__ W,
                                                   unsigned short* __restrict__ WT) {
  __shared__ float tile[32][33];
  const int x0 = blockIdx.x * 32, y0 = blockIdx.y * 32;
  const int tx = threadIdx.x & 31, ty = threadIdx.x >> 5;
#pragma unroll
  for (int j = 0; j < 4; ++j)
    tile[ty + j * 8][tx] = W[(size_t)(y0 + ty + j * 8) * 1024 + x0 + tx];
  __syncthreads();
#pragma unroll
  for (int j = 0; j < 4; ++j)
    WT[(size_t)(x0 + ty + j * 8) * 1024 + y0 + tx] = f2bf(tile[tx][ty + j * 8]);
}

// ---------------------------------------------------------------- projection
// C[t, n] = X[t, :] @ Wq[:, n] + bq[n];  X in {q,k,v} (source-bug faithful).
// g=0 -> qh scaled by 0.125; g=1 -> kh; g=2 -> vhT ([bh][d][s]).
__global__ __launch_bounds__(256) void proj_gemm(
    const float* __restrict__ qin, const float* __restrict__ kin,
    const float* __restrict__ vin, const unsigned short* __restrict__ WqT,
    const float* __restrict__ bq, unsigned short* __restrict__ qh,
    unsigned short* __restrict__ kh, unsigned short* __restrict__ vhT) {
  __shared__ unsigned short As[128 * 72];  // pad 64->72: 144B rows, 16B aligned, 2-way-free banks
  __shared__ unsigned short Bs[128 * 72];
  const int g = blockIdx.z;
  const float* A = (g == 0) ? qin : ((g == 1) ? kin : vin);
  const int n0 = blockIdx.x * 128;
  const int m0 = blockIdx.y * 128;
  const int tid = threadIdx.x;
  const int lane = tid & 63, wave = tid >> 6;
  const int l15 = lane & 15, quad = lane >> 4;
  const int wm = wave >> 1, wn = wave & 1;

  const f32x4 z4 = {0.f, 0.f, 0.f, 0.f};
  f32x4 acc[4][4];
#pragma unroll
  for (int mi = 0; mi < 4; ++mi)
#pragma unroll
    for (int ni = 0; ni < 4; ++ni) acc[mi][ni] = z4;

  for (int kt = 0; kt < 16; ++kt) {
    const int kbase = kt * 64;
#pragma unroll
    for (int i = 0; i < 8; ++i) {  // A: 128x64 fp32 -> bf16
      int c = tid + i * 256;
      int r = c >> 4, c4 = (c & 15) * 4;
      float4 f = *(const float4*)&A[(size_t)(m0 + r) * 1024 + kbase + c4];
      us4 hh;
      hh[0] = f2bf(f.x); hh[1] = f2bf(f.y); hh[2] = f2bf(f.z); hh[3] = f2bf(f.w);
      *(us4*)&As[r * 72 + c4] = hh;
    }
#pragma unroll
    for (int i = 0; i < 4; ++i) {  // B: 128x64 bf16
      int c = tid + i * 256;
      int r = c >> 3, c8 = (c & 7) * 8;
      *(us8*)&Bs[r * 72 + c8] = *(const us8*)&WqT[(size_t)(n0 + r) * 1024 + kbase + c8];
    }
    __syncthreads();
#pragma unroll
    for (int ks = 0; ks < 2; ++ks) {
      short8 af[4], bf8[4];
#pragma unroll
      for (int mi = 0; mi < 4; ++mi)
        af[mi] = *(const short8*)&As[(wm * 64 + mi * 16 + l15) * 72 + ks * 32 + quad * 8];
#pragma unroll
      for (int ni = 0; ni < 4; ++ni)
        bf8[ni] = *(const short8*)&Bs[(wn * 64 + ni * 16 + l15) * 72 + ks * 32 + quad * 8];
#pragma unroll
      for (int mi = 0; mi < 4; ++mi)
#pragma unroll
        for (int ni = 0; ni < 4; ++ni) acc[mi][ni] = MFMA16(af[mi], bf8[ni], acc[mi][ni]);
    }
    __syncthreads();
  }
  // epilogue: C/D layout col=lane&15, row=quad*4+reg (verified m89/m91)
  if (g < 2) {
    unsigned short* out = (g == 0) ? qh : kh;
    const float sc = (g == 0) ? 0.125f : 1.0f;
#pragma unroll
    for (int mi = 0; mi < 4; ++mi)
#pragma unroll
      for (int ni = 0; ni < 4; ++ni) {
        const int col = n0 + wn * 64 + ni * 16 + l15;
        const float bias = bq[col];
#pragma unroll
        for (int r = 0; r < 4; ++r) {
          const int t = m0 + wm * 64 + mi * 16 + quad * 4 + r;
          out[(size_t)t * 1024 + col] = f2bf((acc[mi][ni][r] + bias) * sc);
        }
      }
  } else {
#pragma unroll
    for (int mi = 0; mi < 4; ++mi)
#pragma unroll
      for (int ni = 0; ni < 4; ++ni) {
        const int col = n0 + wn * 64 + ni * 16 + l15;
        const float bias = bq[col];
        const int h = col >> 6, d = col & 63;
        const int tbase = m0 + wm * 64 + mi * 16 + quad * 4;  // 4 consecutive tokens
        const int bb = tbase >> 11, s = tbase & 2047;
        us4 pk;
#pragma unroll
        for (int r = 0; r < 4; ++r) pk[r] = f2bf(acc[mi][ni][r] + bias);
        *(us4*)&vhT[((size_t)(bb * 16 + h) * 64 + d) * 2048 + s] = pk;  // 8B, 32B-segment coalesced
      }
  }
}

// ---------------------------------------------------------------- attention
// block = (q-tile of 128) x (b,h). 4 waves x 32 q-rows each.
// pass1: online (m,l). pass2: recompute scores, write fp32 attn, P->LDS->PV.
__global__ __launch_bounds__(256, 2) void attn_kernel(
    const unsigned short* __restrict__ qh, const unsigned short* __restrict__ kh,
    const unsigned short* __restrict__ vhT, float* __restrict__ attn_out,
    unsigned short* __restrict__ ctx) {
  __shared__ unsigned short Qs[128 * 72];
  __shared__ unsigned short KV[128 * 72];   // K-tile [128][72]; reused as VT [64][136]
  __shared__ unsigned short Ps[128 * 136];
  const int qt = blockIdx.x;
  const int bh = blockIdx.y;
  const int b = bh >> 4, h = bh & 15;
  const int tid = threadIdx.x;
  const int lane = tid & 63, wave = tid >> 6;
  const int l15 = lane & 15, quad = lane >> 4;
  const size_t qrow0 = (size_t)b * 2048 + qt * 128;
  const size_t krow0 = (size_t)b * 2048;

#pragma unroll
  for (int i = 0; i < 4; ++i) {  // stage Q (persistent)
    int c = tid + i * 256;
    int r = c >> 3, d0 = (c & 7) * 8;
    *(us8*)&Qs[r * 72 + d0] = *(const us8*)&qh[(qrow0 + r) * 1024 + h * 64 + d0];
  }
  __syncthreads();
  short8 aQ[2][2];  // A-frags: A[m=lane&15][k=quad*8+j] (guide-verified)
#pragma unroll
  for (int mi = 0; mi < 2; ++mi)
#pragma unroll
    for (int ks = 0; ks < 2; ++ks)
      aQ[mi][ks] = *(const short8*)&Qs[(wave * 32 + mi * 16 + l15) * 72 + ks * 32 + quad * 8];

  float m_[2][4], l_[2][4];
#pragma unroll
  for (int mi = 0; mi < 2; ++mi)
#pragma unroll
    for (int r = 0; r < 4; ++r) { m_[mi][r] = -1e30f; l_[mi][r] = 0.f; }

  const f32x4 z4 = {0.f, 0.f, 0.f, 0.f};

  // ---- pass 1: stats ----
  for (int kt = 0; kt < 16; ++kt) {
    __syncthreads();
#pragma unroll
    for (int i = 0; i < 4; ++i) {
      int c = tid + i * 256;
      int r = c >> 3, d0 = (c & 7) * 8;
      *(us8*)&KV[r * 72 + d0] =
          *(const us8*)&kh[(krow0 + kt * 128 + r) * 1024 + h * 64 + d0];
    }
    __syncthreads();
    f32x4 acc[2][8];
#pragma unroll
    for (int mi = 0; mi < 2; ++mi)
#pragma unroll
      for (int ni = 0; ni < 8; ++ni) acc[mi][ni] = z4;
#pragma unroll
    for (int ks = 0; ks < 2; ++ks) {
      short8 bf8[8];
#pragma unroll
      for (int ni = 0; ni < 8; ++ni)
        bf8[ni] = *(const short8*)&KV[(ni * 16 + l15) * 72 + ks * 32 + quad * 8];
#pragma unroll
      for (int mi = 0; mi < 2; ++mi)
#pragma unroll
        for (int ni = 0; ni < 8; ++ni) acc[mi][ni] = MFMA16(aQ[mi][ks], bf8[ni], acc[mi][ni]);
    }
#pragma unroll
    for (int mi = 0; mi < 2; ++mi)
#pragma unroll
      for (int r = 0; r < 4; ++r) {
        float tm = acc[mi][0][r];
#pragma unroll
        for (int ni = 1; ni < 8; ++ni) tm = fmaxf(tm, acc[mi][ni][r]);
        tm = fmaxf(tm, __shfl_xor(tm, 1));
        tm = fmaxf(tm, __shfl_xor(tm, 2));
        tm = fmaxf(tm, __shfl_xor(tm, 4));
        tm = fmaxf(tm, __shfl_xor(tm, 8));
        const float mn = fmaxf(m_[mi][r], tm);
        float ssum = 0.f;
#pragma unroll
        for (int ni = 0; ni < 8; ++ni) ssum += __expf(acc[mi][ni][r] - mn);
        ssum += __shfl_xor(ssum, 1);
        ssum += __shfl_xor(ssum, 2);
        ssum += __shfl_xor(ssum, 4);
        ssum += __shfl_xor(ssum, 8);
        l_[mi][r] = l_[mi][r] * __expf(m_[mi][r] - mn) + ssum;
        m_[mi][r] = mn;
      }
  }
  float il[2][4];
#pragma unroll
  for (int mi = 0; mi < 2; ++mi)
#pragma unroll
    for (int r = 0; r < 4; ++r) il[mi][r] = 1.0f / l_[mi][r];

  f32x4 oacc[2][4];
#pragma unroll
  for (int mi = 0; mi < 2; ++mi)
#pragma unroll
    for (int ni = 0; ni < 4; ++ni) oacc[mi][ni] = z4;

  // ---- pass 2: attn write + PV ----
  for (int kt = 0; kt < 16; ++kt) {
    __syncthreads();  // prev iter's Ps/KV reads done
#pragma unroll
    for (int i = 0; i < 4; ++i) {
      int c = tid + i * 256;
      int r = c >> 3, d0 = (c & 7) * 8;
      *(us8*)&KV[r * 72 + d0] =
          *(const us8*)&kh[(krow0 + kt * 128 + r) * 1024 + h * 64 + d0];
    }
    __syncthreads();
    f32x4 acc[2][8];
#pragma unroll
    for (int mi = 0; mi < 2; ++mi)
#pragma unroll
      for (int ni = 0; ni < 8; ++ni) acc[mi][ni] = z4;
#pragma unroll
    for (int ks = 0; ks < 2; ++ks) {
      short8 bf8[8];
#pragma unroll
      for (int ni = 0; ni < 8; ++ni)
        bf8[ni] = *(const short8*)&KV[(ni * 16 + l15) * 72 + ks * 32 + quad * 8];
#pragma unroll
      for (int mi = 0; mi < 2; ++mi)
#pragma unroll
        for (int ni = 0; ni < 8; ++ni) acc[mi][ni] = MFMA16(aQ[mi][ks], bf8[ni], acc[mi][ni]);
    }
    __syncthreads();  // all waves done reading K-tile; reuse KV as VT
#pragma unroll
    for (int i = 0; i < 4; ++i) {  // stage V^T [d][s]
      int c = tid + i * 256;
      int d = c >> 4, s0 = (c & 15) * 8;
      *(us8*)&KV[d * 136 + s0] =
          *(const us8*)&vhT[((size_t)bh * 64 + d) * 2048 + kt * 128 + s0];
    }
#pragma unroll
    for (int mi = 0; mi < 2; ++mi)
#pragma unroll
      for (int r = 0; r < 4; ++r) {
        const int rloc = wave * 32 + mi * 16 + quad * 4 + r;
        const float mm = m_[mi][r], sc = il[mi][r];
        const size_t arow = ((size_t)bh * 2048 + qt * 128 + rloc) * 2048 + kt * 128;
#pragma unroll
        for (int ni = 0; ni < 8; ++ni) {
          const float p = __expf(acc[mi][ni][r] - mm) * sc;
          attn_out[arow + ni * 16 + l15] = p;               // exact fp32 attn output
          Ps[rloc * 136 + ni * 16 + l15] = f2bf(p);         // bf16 for PV MFMA
        }
      }
    __syncthreads();  // Ps + VT visible
#pragma unroll
    for (int ks = 0; ks < 4; ++ks) {
      short8 aP[2];
#pragma unroll
      for (int mi = 0; mi < 2; ++mi)
        aP[mi] = *(const short8*)&Ps[(wave * 32 + mi * 16 + l15) * 136 + ks * 32 + quad * 8];
      short8 bV[4];
#pragma unroll
      for (int ni = 0; ni < 4; ++ni)
        bV[ni] = *(const short8*)&KV[(ni * 16 + l15) * 136 + ks * 32 + quad * 8];
#pragma unroll
      for (int mi = 0; mi < 2; ++mi)
#pragma unroll
        for (int ni = 0; ni < 4; ++ni) oacc[mi][ni] = MFMA16(aP[mi], bV[ni], oacc[mi][ni]);
    }
  }
  // ctx store [t, h*64+d] bf16 (already 1/l-normalized)
#pragma unroll
  for (int mi = 0; mi < 2; ++mi)
#pragma unroll
    for (int ni = 0; ni < 4; ++ni)
#pragma unroll
      for (int r = 0; r < 4; ++r) {
        const int rloc = wave * 32 + mi * 16 + quad * 4 + r;
        const int d = ni * 16 + l15;
        ctx[(qrow0 + rloc) * 1024 + h * 64 + d] = f2bf(oacc[mi][ni][r]);
      }
}

// ---------------------------------------------------------------- out proj
// y[t,n] = ctx[t,:] @ Wfc[:,n] + bfc[n] + q[t,n]   (fp32 out, LN comes after)
__global__ __launch_bounds__(256) void out_gemm(
    const unsigned short* __restrict__ ctx, const unsigned short* __restrict__ WfcT,
    const float* __restrict__ bfc, const float* __restrict__ resid,
    float* __restrict__ y) {
  __shared__ unsigned short As[128 * 72];
  __shared__ unsigned short Bs[128 * 72];
  const int n0 = blockIdx.x * 128;
  const int m0 = blockIdx.y * 128;
  const int tid = threadIdx.x;
  const int lane = tid & 63, wave = tid >> 6;
  const int l15 = lane & 15, quad = lane >> 4;
  const int wm = wave >> 1, wn = wave & 1;

  const f32x4 z4 = {0.f, 0.f, 0.f, 0.f};
  f32x4 acc[4][4];
#pragma unroll
  for (int mi = 0; mi < 4; ++mi)
#pragma unroll
    for (int ni = 0; ni < 4; ++ni) acc[mi][ni] = z4;

  for (int kt = 0; kt < 16; ++kt) {
    const int kbase = kt * 64;
#pragma unroll
    for (int i = 0; i < 4; ++i) {
      int c = tid + i * 256;
      int r = c >> 3, c8 = (c & 7) * 8;
      *(us8*)&As[r * 72 + c8] = *(const us8*)&ctx[(size_t)(m0 + r) * 1024 + kbase + c8];
      *(us8*)&Bs[r * 72 + c8] = *(const us8*)&WfcT[(size_t)(n0 + r) * 1024 + kbase + c8];
    }
    __syncthreads();
#pragma unroll
    for (int ks = 0; ks < 2; ++ks) {
      short8 af[4], bf8[4];
#pragma unroll
      for (int mi = 0; mi < 4; ++mi)
        af[mi] = *(const short8*)&As[(wm * 64 + mi * 16 + l15) * 72 + ks * 32 + quad * 8];
#pragma unroll
      for (int ni = 0; ni < 4; ++ni)
        bf8[ni] = *(const short8*)&Bs[(wn * 64 + ni * 16 + l15) * 72 + ks * 32 + quad * 8];
#pragma unroll
      for (int mi = 0; mi < 4; ++mi)
#pragma unroll
        for (int ni = 0; ni < 4; ++ni) acc[mi][ni] = MFMA16(af[mi], bf8[ni], acc[mi][ni]);
    }
    __syncthreads();
  }
#pragma unroll
  for (int mi = 0; mi < 4; ++mi)
#pragma unroll
    for (int ni = 0; ni < 4; ++ni) {
      const int col = n0 + wn * 64 + ni * 16 + l15;
      const float bias = bfc[col];
#pragma unroll
      for (int r = 0; r < 4; ++r) {
        const int t = m0 + wm * 64 + mi * 16 + quad * 4 + r;
        y[(size_t)t * 1024 + col] = acc[mi][ni][r] + bias + resid[(size_t)t * 1024 + col];
      }
    }
}

// ---------------------------------------------------------------- layernorm (in-place)
__global__ __launch_bounds__(256) void ln_kernel(float* __restrict__ x,
                                                 const float* __restrict__ gamma,
                                                 const float* __restrict__ beta) {
  const int t = blockIdx.x;
  const int tid = threadIdx.x;
  float4 v = ((const float4*)x)[(size_t)t * 256 + tid];
  float s = v.x + v.y + v.z + v.w;
  float ss = v.x * v.x + v.y * v.y + v.z * v.z + v.w * v.w;
#pragma unroll
  for (int mask = 1; mask < 64; mask <<= 1) {
    s += __shfl_xor(s, mask);
    ss += __shfl_xor(ss, mask);
  }
  __shared__ float red[8];
  const int wave = tid >> 6, lane = tid & 63;
  if (lane == 0) { red[wave] = s; red[4 + wave] = ss; }
  __syncthreads();
  s = red[0] + red[1] + red[2] + red[3];
  ss = red[4] + red[5] + red[6] + red[7];
  const float mu = s * (1.f / 1024.f);
  const float var = ss * (1.f / 1024.f) - mu * mu;
  const float rs = rsqrtf(var + 1e-6f);
  const float4 gm = ((const float4*)gamma)[tid];
  const float4 bt = ((const float4*)beta)[tid];
  v.x = (v.x - mu) * rs * gm.x + bt.x;
  v.y = (v.y - mu) * rs * gm.y + bt.y;
  v.z = (v.z - mu) * rs * gm.z + bt.z;
  v.w = (v.w - mu) * rs * gm.w + bt.w;
  ((float4*)x)[(size_t)t * 256 + tid] = v;
}

// ---------------------------------------------------------------- launch
extern "C" void kernel_launch(void* const* d_in, const int* in_sizes, int n_in,
                              void* d_out, int out_size, void* d_ws, size_t ws_size,
                              hipStream_t stream) {
  const float* q = (const float*)d_in[0];
  const float* k = (const float*)d_in[1];
  const float* v = (const float*)d_in[2];
  const float* Wq = (const float*)d_in[3];
  const float* bq = (const float*)d_in[4];
  const float* Wfc = (const float*)d_in[5];
  const float* bfc = (const float*)d_in[6];
  const float* gamma = (const float*)d_in[7];
  const float* beta = (const float*)d_in[8];

  float* out_x = (float*)d_out;
  float* out_attn = out_x + (size_t)4 * 2048 * 1024;  // x first, then attn

  char* ws = (char*)d_ws;  // needs >= 68 MB
  unsigned short* ws_qh = (unsigned short*)(ws);
  unsigned short* ws_kh = (unsigned short*)(ws + ((size_t)16 << 20));
  unsigned short* ws_vhT = (unsigned short*)(ws + ((size_t)32 << 20));
  unsigned short* ws_ctx = (unsigned short*)(ws + ((size_t)48 << 20));
  unsigned short* ws_WqT = (unsigned short*)(ws + ((size_t)64 << 20));
  unsigned short* ws_WfcT = (unsigned short*)(ws + ((size_t)66 << 20));

  transpose_w<<<dim3(32, 32), 256, 0, stream>>>(Wq, ws_WqT);
  transpose_w<<<dim3(32, 32), 256, 0, stream>>>(Wfc, ws_WfcT);
  proj_gemm<<<dim3(8, 64, 3), 256, 0, stream>>>(q, k, v, ws_WqT, bq, ws_qh, ws_kh, ws_vhT);
  attn_kernel<<<dim3(16, 64), 256, 0, stream>>>(ws_qh, ws_kh, ws_vhT, out_attn, ws_ctx);
  out_gemm<<<dim3(8, 64), 256, 0, stream>>>(ws_ctx, ws_WfcT, bfc, q, out_x);
  ln_kernel<<<8192, 256, 0, stream>>>(out_x, gamma, beta);
}